// Round 1
// baseline (766.620 us; speedup 1.0000x reference)
//
#include <hip/hip_runtime.h>

// Head: B=4, T=2048, N_EMB=1024, HEAD_DIM=64.
// Reference bug replicated: k = x @ Wq^T (Wk unused). So K == Q.
// Plan: kernel 1 computes q = x@Wq^T and v = x@Wv^T into workspace (fp32).
//       kernel 2 is causal flash attention with K = Q.

#define T_SEQ 2048
#define NBATCH 4
#define BT 8192   // B*T

// ---------------- Kernel 1: fused q/v projection GEMM ----------------
// C[8192][128] = x[8192][1024] @ [Wq;Wv]^T.  Tile 64 rows x 128 cols, BK=64.
// 256 threads, per-thread 4x8 register tile. LDS operands stored as
// float4 with XOR swizzle (slot = c ^ (row&15)) so per-lane-row reads
// don't hit the stride-256B 32-way bank conflict.
__global__ __launch_bounds__(256) void proj_kernel(
    const float* __restrict__ x, const float* __restrict__ Wq,
    const float* __restrict__ Wv, float* __restrict__ q_ws,
    float* __restrict__ v_ws)
{
    __shared__ float4 xs[64][16];    // [row][slot]
    __shared__ float4 wsm[128][16];  // [outcol][slot]
    const int tid = threadIdx.x;
    const int r0 = blockIdx.x * 64;
    const int ty = tid >> 4;   // 0..15 -> rows ty*4..+3
    const int tx = tid & 15;   // 0..15 -> cols tx*8..+7

    float acc[4][8];
#pragma unroll
    for (int i = 0; i < 4; ++i)
#pragma unroll
        for (int j = 0; j < 8; ++j) acc[i][j] = 0.f;

    for (int k0 = 0; k0 < 1024; k0 += 64) {
        __syncthreads();
#pragma unroll
        for (int i = 0; i < 4; ++i) {
            int f = tid + i * 256;
            int row = f >> 4, c = f & 15;
            xs[row][c ^ (row & 15)] =
                *reinterpret_cast<const float4*>(x + (size_t)(r0 + row) * 1024 + k0 + c * 4);
        }
#pragma unroll
        for (int i = 0; i < 8; ++i) {
            int f = tid + i * 256;
            int row = f >> 4, c = f & 15;
            const float* src = (row < 64) ? (Wq + (size_t)row * 1024)
                                          : (Wv + (size_t)(row - 64) * 1024);
            wsm[row][c ^ (row & 15)] =
                *reinterpret_cast<const float4*>(src + k0 + c * 4);
        }
        __syncthreads();
#pragma unroll
        for (int k4 = 0; k4 < 16; ++k4) {
            float4 a4[4], b4[8];
#pragma unroll
            for (int i = 0; i < 4; ++i) {
                int row = ty * 4 + i;
                a4[i] = xs[row][k4 ^ (row & 15)];
            }
#pragma unroll
            for (int j = 0; j < 8; ++j) {
                int row = tx * 8 + j;
                b4[j] = wsm[row][k4 ^ (row & 15)];
            }
#pragma unroll
            for (int i = 0; i < 4; ++i)
#pragma unroll
                for (int j = 0; j < 8; ++j)
                    acc[i][j] += a4[i].x * b4[j].x + a4[i].y * b4[j].y +
                                 a4[i].z * b4[j].z + a4[i].w * b4[j].w;
        }
    }

#pragma unroll
    for (int i = 0; i < 4; ++i) {
        int row = r0 + ty * 4 + i;
        float4 lo = make_float4(acc[i][0], acc[i][1], acc[i][2], acc[i][3]);
        float4 hi = make_float4(acc[i][4], acc[i][5], acc[i][6], acc[i][7]);
        if (tx < 8) {
            float* dst = q_ws + (size_t)row * 64 + tx * 8;
            *reinterpret_cast<float4*>(dst)     = lo;
            *reinterpret_cast<float4*>(dst + 4) = hi;
        } else {
            float* dst = v_ws + (size_t)row * 64 + (tx - 8) * 8;
            *reinterpret_cast<float4*>(dst)     = lo;
            *reinterpret_cast<float4*>(dst + 4) = hi;
        }
    }
}

// ---------------- Kernel 2: causal flash attention, K = Q ----------------
// Grid (64 qblocks, 4 batches); QBLK=32 rows/block, KBLK=64 keys/tile.
// 4 waves; wave w owns rows w*8..w*8+7, lane = key index (scores) and
// lane = output dim (PV). Online softmax (m,l per row).
__global__ __launch_bounds__(256) void attn_kernel(
    const float* __restrict__ q_ws, const float* __restrict__ v_ws,
    float* __restrict__ out)
{
    __shared__ float4 Qs[32][16];   // natural: reads are wave-uniform (broadcast)
    __shared__ float4 Ks[64][16];   // XOR-swizzled: per-lane-row reads
    __shared__ float  Vs[64][64];   // natural: Vs[s][lane] is conflict-free
    __shared__ float4 Ps[32][16];   // natural: reads are wave-uniform

    const int tid = threadIdx.x;
    const int wv = tid >> 6;
    const int lane = tid & 63;
    const int qb = blockIdx.x;
    const int b = blockIdx.y;
    const int t0 = qb * 32;
    const float* qb_ptr = q_ws + (size_t)b * T_SEQ * 64;
    const float* vb_ptr = v_ws + (size_t)b * T_SEQ * 64;

#pragma unroll
    for (int i = 0; i < 2; ++i) {
        int f = tid + i * 256;
        int row = f >> 4, c = f & 15;
        Qs[row][c] = *reinterpret_cast<const float4*>(
            qb_ptr + (size_t)(t0 + row) * 64 + c * 4);
    }

    float m[8], l[8], acc[8];
#pragma unroll
    for (int r = 0; r < 8; ++r) { m[r] = -1e30f; l[r] = 0.f; acc[r] = 0.f; }

    const int ntiles = (t0 + 95) >> 6;  // keys 0 .. t0+31 inclusive
    for (int tile = 0; tile < ntiles; ++tile) {
        const int s0 = tile * 64;
        __syncthreads();  // previous tile's PV reads done before overwrite
#pragma unroll
        for (int i = 0; i < 4; ++i) {
            int f = tid + i * 256;
            int row = f >> 4, c = f & 15;
            Ks[row][c ^ (row & 15)] = *reinterpret_cast<const float4*>(
                qb_ptr + (size_t)(s0 + row) * 64 + c * 4);
            *reinterpret_cast<float4*>(&Vs[row][c * 4]) =
                *reinterpret_cast<const float4*>(
                    vb_ptr + (size_t)(s0 + row) * 64 + c * 4);
        }
        __syncthreads();

        // hoist this lane's K row (key = s0+lane) into registers
        float4 k4[16];
#pragma unroll
        for (int d4 = 0; d4 < 16; ++d4) k4[d4] = Ks[lane][d4 ^ (lane & 15)];

#pragma unroll
        for (int r = 0; r < 8; ++r) {
            const int rl = wv * 8 + r;
            float s = 0.f;
#pragma unroll
            for (int d4 = 0; d4 < 16; ++d4) {
                float4 q4 = Qs[rl][d4];
                s += q4.x * k4[d4].x + q4.y * k4[d4].y +
                     q4.z * k4[d4].z + q4.w * k4[d4].w;
            }
            s *= 0.125f;  // 64^-0.5
            const int tg = t0 + rl;
            const int sg = s0 + lane;
            if (sg > tg) s = -1e30f;  // causal mask

            float mc = s;
#pragma unroll
            for (int o = 32; o > 0; o >>= 1) mc = fmaxf(mc, __shfl_xor(mc, o, 64));
            const float mn = fmaxf(m[r], mc);
            const float p = __expf(s - mn);
            float ls = p;
#pragma unroll
            for (int o = 32; o > 0; o >>= 1) ls += __shfl_xor(ls, o, 64);
            const float sc = __expf(m[r] - mn);
            l[r] = l[r] * sc + ls;
            m[r] = mn;
            acc[r] *= sc;
            reinterpret_cast<float*>(&Ps[rl][0])[lane] = p;
        }
        __syncthreads();  // Ps visible (and ordered) before PV

        // PV: acc[r] (col=lane) += sum_s P[r][s] * V[s][lane]
#pragma unroll
        for (int s4 = 0; s4 < 16; ++s4) {
            const float v0 = Vs[s4 * 4 + 0][lane];
            const float v1 = Vs[s4 * 4 + 1][lane];
            const float v2 = Vs[s4 * 4 + 2][lane];
            const float v3 = Vs[s4 * 4 + 3][lane];
#pragma unroll
            for (int r = 0; r < 8; ++r) {
                float4 p4 = Ps[wv * 8 + r][s4];
                acc[r] += p4.x * v0 + p4.y * v1 + p4.z * v2 + p4.w * v3;
            }
        }
    }

#pragma unroll
    for (int r = 0; r < 8; ++r) {
        const int t = t0 + wv * 8 + r;
        out[((size_t)b * T_SEQ + t) * 64 + lane] = acc[r] / l[r];
    }
}

extern "C" void kernel_launch(void* const* d_in, const int* in_sizes, int n_in,
                              void* d_out, int out_size, void* d_ws, size_t ws_size,
                              hipStream_t stream) {
    const float* x  = (const float*)d_in[0];
    const float* Wq = (const float*)d_in[1];
    // d_in[2] = Wk: unused (reference bug: key = query projection)
    const float* Wv = (const float*)d_in[3];
    float* outp = (float*)d_out;

    float* q_ws = (float*)d_ws;                  // 8192*64 fp32 = 2 MB
    float* v_ws = q_ws + (size_t)BT * 64;        // 2 MB

    proj_kernel<<<dim3(BT / 64), dim3(256), 0, stream>>>(x, Wq, Wv, q_ws, v_ws);
    attn_kernel<<<dim3(T_SEQ / 32, NBATCH), dim3(256), 0, stream>>>(q_ws, v_ws, outp);
}

// Round 2
// 65.591 us; speedup vs baseline: 11.6878x; 11.6878x over previous
//
#include <hip/hip_runtime.h>

// Head: B=4, T=2048, N_EMB=1024, HEAD_DIM=64. Reference bug: K = x@Wq (Wk unused).
// Pipeline: wconv (W->bf16) ; proj (bf16 MFMA GEMM -> qb row-major + v transposed) ;
// attn (flash, K==Q, MFMA QK^T/PV, 4-way key-split per 16-row q chunk + merge).

#define T_SEQ 2048
#define NB 4

typedef __attribute__((ext_vector_type(8))) short bf16x8;
typedef __attribute__((ext_vector_type(4))) float f32x4;

union V16 { uint4 u; bf16x8 b; };

__device__ __forceinline__ unsigned short f2b(float x) {
    union { float f; unsigned u; } a; a.f = x;
    return (unsigned short)((a.u + 0x7FFFu + ((a.u >> 16) & 1u)) >> 16);
}

// ---------------- kernel 0: W fp32 -> bf16 ([Wq;Wv] as [128][1024]) ----------------
__global__ __launch_bounds__(256) void wconv(const float* __restrict__ Wq,
                                             const float* __restrict__ Wv,
                                             unsigned short* __restrict__ wb)
{
    const int e = (blockIdx.x * 256 + threadIdx.x) * 8;
    const float* s = (e < 65536) ? (Wq + e) : (Wv + (e - 65536));
    float4 f0 = *(const float4*)(s);
    float4 f1 = *(const float4*)(s + 4);
    uint4 o;
    o.x = f2b(f0.x) | ((unsigned)f2b(f0.y) << 16);
    o.y = f2b(f0.z) | ((unsigned)f2b(f0.w) << 16);
    o.z = f2b(f1.x) | ((unsigned)f2b(f1.y) << 16);
    o.w = f2b(f1.z) | ((unsigned)f2b(f1.w) << 16);
    *(uint4*)(wb + e) = o;
}

// ---------------- kernel 1: projection GEMM (bf16 MFMA) ----------------
// C[8192][128] = x[8192][1024] @ W^T.  BM=32, BN=128, BK=64, 4 waves (2x2),
// wave tile 16x64, mfma_f32_16x16x32_bf16. Outputs: qb[t][64] bf16 (cols 0-63),
// vbT[b][d][t] bf16 (cols 64-127, transposed for attention's PV B-frags).
__global__ __launch_bounds__(256) void proj_kernel(
    const float* __restrict__ x, const unsigned short* __restrict__ wb,
    unsigned short* __restrict__ qb, unsigned short* __restrict__ vbT)
{
    __shared__ __align__(16) unsigned char sm[4096 + 16384];
    unsigned char* As = sm;            // [32 rows][8 slots of 16B], slot ^= row&7
    unsigned char* Bs = sm + 4096;     // [128 rows][8 slots of 16B]
    const int tid = threadIdx.x;
    const int lane = tid & 63;
    const int l15 = lane & 15, lg = lane >> 4;
    const int w = tid >> 6;
    const int wr = w >> 1, wc = w & 1;
    const int r0 = blockIdx.x * 32;

    const int srow = tid >> 3, sc = tid & 7;          // staging coords
    const float* xsrc = x + (size_t)(r0 + srow) * 1024 + sc * 8;
    const unsigned aoff = srow * 128 + ((sc ^ (srow & 7)) << 4);

    f32x4 acc[4];
#pragma unroll
    for (int nj = 0; nj < 4; ++nj)
#pragma unroll
        for (int j = 0; j < 4; ++j) acc[nj][j] = 0.f;

    const int arow = wr * 16 + l15;
    const unsigned abase = (unsigned)arow * 128;
    const unsigned slx = (unsigned)(l15 & 7);

    // prefetch k0 = 0
    float4 xa = *(const float4*)(xsrc);
    float4 xb = *(const float4*)(xsrc + 4);
    uint4 wv4[4];
#pragma unroll
    for (int i = 0; i < 4; ++i)
        wv4[i] = *(const uint4*)(wb + (size_t)(srow + i * 32) * 1024 + sc * 8);

    for (int k0 = 0; k0 < 1024; k0 += 64) {
        if (k0) __syncthreads();                      // all waves done reading LDS
        uint4 xc;
        xc.x = f2b(xa.x) | ((unsigned)f2b(xa.y) << 16);
        xc.y = f2b(xa.z) | ((unsigned)f2b(xa.w) << 16);
        xc.z = f2b(xb.x) | ((unsigned)f2b(xb.y) << 16);
        xc.w = f2b(xb.z) | ((unsigned)f2b(xb.w) << 16);
        *(uint4*)(As + aoff) = xc;
#pragma unroll
        for (int i = 0; i < 4; ++i)
            *(uint4*)(Bs + i * 4096 + aoff) = wv4[i];
        __syncthreads();
        if (k0 < 960) {                               // prefetch next tile
            xa = *(const float4*)(xsrc + k0 + 64);
            xb = *(const float4*)(xsrc + k0 + 68);
#pragma unroll
            for (int i = 0; i < 4; ++i)
                wv4[i] = *(const uint4*)(wb + (size_t)(srow + i * 32) * 1024 + k0 + 64 + sc * 8);
        }
#pragma unroll
        for (int ks = 0; ks < 2; ++ks) {
            V16 a;
            a.u = *(const uint4*)(As + abase + (((((unsigned)ks << 2) | lg) ^ slx) << 4));
#pragma unroll
            for (int nj = 0; nj < 4; ++nj) {
                V16 bf;
                const unsigned brow = wc * 64 + nj * 16 + l15;
                bf.u = *(const uint4*)(Bs + brow * 128 + (((((unsigned)ks << 2) | lg) ^ slx) << 4));
                acc[nj] = __builtin_amdgcn_mfma_f32_16x16x32_bf16(a.b, bf.b, acc[nj], 0, 0, 0);
            }
        }
    }

    // epilogue: C row = (lg*4 + r) within wave tile, col = wc*64 + nj*16 + l15
    const int trow0 = r0 + wr * 16 + lg * 4;
    if (wc == 0) {
#pragma unroll
        for (int nj = 0; nj < 4; ++nj) {
            const int col = nj * 16 + l15;
#pragma unroll
            for (int r = 0; r < 4; ++r)
                qb[(size_t)(trow0 + r) * 64 + col] = f2b(acc[nj][r]);
        }
    } else {
        const int b = r0 >> 11;
        const int tloc = (r0 & 2047) + wr * 16 + lg * 4;
#pragma unroll
        for (int nj = 0; nj < 4; ++nj) {
            const int d = nj * 16 + l15;
            uint2 p;
            p.x = f2b(acc[nj][0]) | ((unsigned)f2b(acc[nj][1]) << 16);
            p.y = f2b(acc[nj][2]) | ((unsigned)f2b(acc[nj][3]) << 16);
            *(uint2*)(vbT + (size_t)(b * 64 + d) * 2048 + tloc) = p;
        }
    }
}

// ---------------- kernel 2: causal flash attention (K == Q), bf16 MFMA ----------------
// Block: one 16-row q chunk, 4 waves split 64-key tiles round-robin, merge at end.
// Grid (128 chunks, 4 batches) = 512 blocks; heavy chunks dispatched first.
__global__ __launch_bounds__(256) void attn_kernel(
    const unsigned short* __restrict__ qb, const unsigned short* __restrict__ vbT,
    float* __restrict__ out)
{
    __shared__ __align__(16) unsigned short Ps[4][16 * 64];  // per-wave P tile, swizzled
    __shared__ float Om[4][16][64];
    __shared__ float Mm[4][16];
    __shared__ float Lm[4][16];

    const int tid = threadIdx.x;
    const int w = tid >> 6, lane = tid & 63;
    const int l15 = lane & 15, lg = lane >> 4;
    const int chunk = 127 - blockIdx.x;               // heaviest first
    const int b = blockIdx.y;
    const int qrow0 = chunk * 16;
    const unsigned short* qbb = qb + (size_t)b * T_SEQ * 64;
    const unsigned short* vbb = vbT + (size_t)b * 64 * T_SEQ;

    // Q A-fragments (row = l15, k = ks*32 + lg*8 + r)
    V16 qf[2];
#pragma unroll
    for (int ks = 0; ks < 2; ++ks)
        qf[ks].u = *(const uint4*)(qbb + (size_t)(qrow0 + l15) * 64 + ks * 32 + lg * 8);

    f32x4 o[4];
    float m[4], lv[4];
#pragma unroll
    for (int p = 0; p < 4; ++p)
#pragma unroll
        for (int j = 0; j < 4; ++j) o[p][j] = 0.f;
#pragma unroll
    for (int r = 0; r < 4; ++r) { m[r] = -1e30f; lv[r] = 0.f; }

    unsigned short* ps = Ps[w];
    const int ntiles = (qrow0 + 79) >> 6;

    for (int t = w; t < ntiles; t += 4) {
        const int s0 = t * 64;
        // K fragments (K == Q), direct from cache: B[k=dim][col=key]
        V16 kf[4][2];
#pragma unroll
        for (int nj = 0; nj < 4; ++nj)
#pragma unroll
            for (int ks = 0; ks < 2; ++ks)
                kf[nj][ks].u = *(const uint4*)(qbb + (size_t)(s0 + nj * 16 + l15) * 64 + ks * 32 + lg * 8);
        f32x4 s[4];
#pragma unroll
        for (int nj = 0; nj < 4; ++nj) {
#pragma unroll
            for (int j = 0; j < 4; ++j) s[nj][j] = 0.f;
#pragma unroll
            for (int ks = 0; ks < 2; ++ks)
                s[nj] = __builtin_amdgcn_mfma_f32_16x16x32_bf16(qf[ks].b, kf[nj][ks].b, s[nj], 0, 0, 0);
        }
        // V fragments issued early (independent of softmax): B[k=key][col=dim] from vbT[d][t]
        V16 vf[4][2];
#pragma unroll
        for (int p = 0; p < 4; ++p)
#pragma unroll
            for (int ks = 0; ks < 2; ++ks)
                vf[p][ks].u = *(const uint4*)(vbb + (size_t)(p * 16 + l15) * 2048 + s0 + ks * 32 + lg * 8);

        // scale + causal mask (D: row = lg*4 + r, col = l15)
        if (s0 + 63 > qrow0) {
#pragma unroll
            for (int nj = 0; nj < 4; ++nj) {
                const int key = s0 + nj * 16 + l15;
#pragma unroll
                for (int r = 0; r < 4; ++r) {
                    float sv = s[nj][r] * 0.125f;
                    if (key > qrow0 + lg * 4 + r) sv = -1e30f;
                    s[nj][r] = sv;
                }
            }
        } else {
#pragma unroll
            for (int nj = 0; nj < 4; ++nj)
#pragma unroll
                for (int r = 0; r < 4; ++r) s[nj][r] *= 0.125f;
        }
        // online softmax (rows live in 16-lane groups -> xor 1,2,4,8)
        float fr[4];
#pragma unroll
        for (int r = 0; r < 4; ++r) {
            float mc = fmaxf(fmaxf(s[0][r], s[1][r]), fmaxf(s[2][r], s[3][r]));
            mc = fmaxf(mc, __shfl_xor(mc, 1));
            mc = fmaxf(mc, __shfl_xor(mc, 2));
            mc = fmaxf(mc, __shfl_xor(mc, 4));
            mc = fmaxf(mc, __shfl_xor(mc, 8));
            const float mn = fmaxf(m[r], mc);
            fr[r] = __expf(m[r] - mn);
            m[r] = mn;
        }
#pragma unroll
        for (int nj = 0; nj < 4; ++nj)
#pragma unroll
            for (int r = 0; r < 4; ++r) s[nj][r] = __expf(s[nj][r] - m[r]);
#pragma unroll
        for (int r = 0; r < 4; ++r) {
            float ls = s[0][r] + s[1][r] + s[2][r] + s[3][r];
            ls += __shfl_xor(ls, 1);
            ls += __shfl_xor(ls, 2);
            ls += __shfl_xor(ls, 4);
            ls += __shfl_xor(ls, 8);
            lv[r] = lv[r] * fr[r] + ls;
        }
#pragma unroll
        for (int p = 0; p < 4; ++p)
#pragma unroll
            for (int r = 0; r < 4; ++r) o[p][r] *= fr[r];

        // P -> per-wave LDS [16 rows][64 keys] bf16, 16B-slot XOR swizzle
#pragma unroll
        for (int nj = 0; nj < 4; ++nj) {
            const int col = nj * 16 + l15;
            const int sl = col >> 3, cr = col & 7;
#pragma unroll
            for (int r = 0; r < 4; ++r) {
                const int row = lg * 4 + r;
                ps[row * 64 + ((sl ^ (row & 7)) << 3) + cr] = f2b(s[nj][r]);
            }
        }
        // PV: A = P (row = l15, k = keys), B = V fragments
#pragma unroll
        for (int ks = 0; ks < 2; ++ks) {
            V16 pa;
            pa.u = *(const uint4*)((const unsigned char*)ps + l15 * 128 +
                                   (((((unsigned)ks << 2) | lg) ^ (unsigned)(l15 & 7)) << 4));
#pragma unroll
            for (int p = 0; p < 4; ++p)
                o[p] = __builtin_amdgcn_mfma_f32_16x16x32_bf16(pa.b, vf[p][ks].b, o[p], 0, 0, 0);
        }
    }

    // merge the 4 per-wave softmax states
#pragma unroll
    for (int p = 0; p < 4; ++p)
#pragma unroll
        for (int r = 0; r < 4; ++r)
            Om[w][lg * 4 + r][p * 16 + l15] = o[p][r];
    if (l15 == 0) {
#pragma unroll
        for (int r = 0; r < 4; ++r) { Mm[w][lg * 4 + r] = m[r]; Lm[w][lg * 4 + r] = lv[r]; }
    }
    __syncthreads();

    const int row = tid >> 4, d0 = (tid & 15) * 4;
    const float M = fmaxf(fmaxf(Mm[0][row], Mm[1][row]), fmaxf(Mm[2][row], Mm[3][row]));
    float L = 0.f;
    float ax = 0.f, ay = 0.f, az = 0.f, aw = 0.f;
#pragma unroll
    for (int ww = 0; ww < 4; ++ww) {
        const float e = __expf(Mm[ww][row] - M);
        L += e * Lm[ww][row];
        const float4 ov = *(const float4*)&Om[ww][row][d0];
        ax += e * ov.x; ay += e * ov.y; az += e * ov.z; aw += e * ov.w;
    }
    const float inv = 1.f / L;
    *(float4*)(out + ((size_t)b * T_SEQ + qrow0 + row) * 64 + d0) =
        make_float4(ax * inv, ay * inv, az * inv, aw * inv);
}

extern "C" void kernel_launch(void* const* d_in, const int* in_sizes, int n_in,
                              void* d_out, int out_size, void* d_ws, size_t ws_size,
                              hipStream_t stream) {
    const float* x  = (const float*)d_in[0];
    const float* Wq = (const float*)d_in[1];
    // d_in[2] = Wk: unused (reference bug: key = query projection)
    const float* Wv = (const float*)d_in[3];
    float* outp = (float*)d_out;

    unsigned short* qbw = (unsigned short*)d_ws;          // 8192*64 bf16 = 1 MB
    unsigned short* vbw = qbw + 8192 * 64;                // 1 MB (transposed v)
    unsigned short* wbw = vbw + 8192 * 64;                // 256 KB ([Wq;Wv] bf16)

    wconv<<<64, 256, 0, stream>>>(Wq, Wv, wbw);
    proj_kernel<<<256, 256, 0, stream>>>(x, wbw, qbw, vbw);
    attn_kernel<<<dim3(128, NB), dim3(256), 0, stream>>>(qbw, vbw, outp);
}

// Round 3
// 45.609 us; speedup vs baseline: 16.8086x; 1.4381x over previous
//
#include <hip/hip_runtime.h>

// Head: B=4, T=2048, N_EMB=1024, HEAD_DIM=64. Reference bug: K = x@Wq (Wk unused).
// wconv (W->bf16) ; proj (bf16 MFMA GEMM, dbuf LDS, global_load_lds for W) ;
// attn (flash, K==Q, MFMA, 4-way key-split + K-prefetch + defer-max).

#define T_SEQ 2048
#define NB 4

typedef __attribute__((ext_vector_type(8))) short bf16x8;
typedef __attribute__((ext_vector_type(4))) float f32x4;

union V16 { uint4 u; bf16x8 b; };

__device__ __forceinline__ unsigned short f2b(float x) {
    union { float f; unsigned u; } a; a.f = x;
    return (unsigned short)((a.u + 0x7FFFu + ((a.u >> 16) & 1u)) >> 16);
}

__device__ __forceinline__ void gl_lds16(const unsigned short* g, unsigned short* l) {
    __builtin_amdgcn_global_load_lds(
        (const __attribute__((address_space(1))) unsigned int*)g,
        (__attribute__((address_space(3))) unsigned int*)l, 16, 0, 0);
}

// ---------------- kernel 0: W fp32 -> bf16 ([Wq;Wv] as [128][1024]) ----------------
__global__ __launch_bounds__(256) void wconv(const float* __restrict__ Wq,
                                             const float* __restrict__ Wv,
                                             unsigned short* __restrict__ wb)
{
    const int e = (blockIdx.x * 256 + threadIdx.x) * 8;
    const float* s = (e < 65536) ? (Wq + e) : (Wv + (e - 65536));
    float4 f0 = *(const float4*)(s);
    float4 f1 = *(const float4*)(s + 4);
    uint4 o;
    o.x = f2b(f0.x) | ((unsigned)f2b(f0.y) << 16);
    o.y = f2b(f0.z) | ((unsigned)f2b(f0.w) << 16);
    o.z = f2b(f1.x) | ((unsigned)f2b(f1.y) << 16);
    o.w = f2b(f1.z) | ((unsigned)f2b(f1.w) << 16);
    *(uint4*)(wb + e) = o;
}

// ---------------- kernel 1: projection GEMM (bf16 MFMA, dbuf) ----------------
// C[8192][128] = x[8192][1024] @ W^T. BM=32, BN=128, BK=128, 512 thr (8 waves 2x4),
// wave tile 16x32. LDS [row][16 slots of 16B], slot XOR (row&15).
// W staged by global_load_lds with pre-swizzled per-lane source; x reg-staged+cvt.
__global__ __launch_bounds__(512) void proj_kernel(
    const float* __restrict__ x, const unsigned short* __restrict__ wb,
    unsigned short* __restrict__ qb, unsigned short* __restrict__ vbT)
{
    __shared__ __align__(16) unsigned short As[2][32 * 128];   // 8 KB each
    __shared__ __align__(16) unsigned short Bs[2][128 * 128];  // 32 KB each

    const int tid = threadIdx.x;
    const int lane = tid & 63;
    const int w = tid >> 6;
    const int l15 = lane & 15, lg = lane >> 4;
    const int wr = w >> 2, wn = w & 3;   // 2(M) x 4(N); wave tile 16 x 32
    const int r0 = blockIdx.x * 32;

    // x staging: thread -> row tid>>4 (0..31), 8 floats at col (tid&15)*8
    const int sxr = tid >> 4, sxc = tid & 15;
    const float* xsrc = x + (size_t)(r0 + sxr) * 1024 + sxc * 8;
    const unsigned axoff = sxr * 128 + ((sxc ^ (sxr & 15)) * 8);  // ushort idx

    // W staging: inst i covers rows w*16+i*4..+3; lane l -> row += l>>4, slot l&15,
    // source col pre-swizzled so linear LDS dest == swizzled image.
    const unsigned short* wsrc[4];
    unsigned wldo[4];
#pragma unroll
    for (int i = 0; i < 4; ++i) {
        const int row = w * 16 + i * 4 + (lane >> 4);
        const int slot = lane & 15;
        wsrc[i] = wb + (size_t)row * 1024 + (slot ^ (row & 15)) * 8;
        wldo[i] = (unsigned)(w * 16 + i * 4) * 128;
    }

    f32x4 acc[2];
#pragma unroll
    for (int nj = 0; nj < 2; ++nj)
#pragma unroll
        for (int j = 0; j < 4; ++j) acc[nj][j] = 0.f;

    const int arow = wr * 16 + l15;

    // prologue: stage k-tile 0
    float4 xa = *(const float4*)(xsrc);
    float4 xb = *(const float4*)(xsrc + 4);
#pragma unroll
    for (int i = 0; i < 4; ++i) gl_lds16(wsrc[i], &Bs[0][wldo[i]]);
    {
        uint4 xc;
        xc.x = f2b(xa.x) | ((unsigned)f2b(xa.y) << 16);
        xc.y = f2b(xa.z) | ((unsigned)f2b(xa.w) << 16);
        xc.z = f2b(xb.x) | ((unsigned)f2b(xb.y) << 16);
        xc.w = f2b(xb.z) | ((unsigned)f2b(xb.w) << 16);
        *(uint4*)(&As[0][axoff]) = xc;
    }
    __syncthreads();

    for (int t = 0; t < 8; ++t) {
        const int cur = t & 1;
        if (t < 7) {  // issue next tile's loads early
            const int k0 = (t + 1) * 128;
            xa = *(const float4*)(xsrc + k0);
            xb = *(const float4*)(xsrc + k0 + 4);
#pragma unroll
            for (int i = 0; i < 4; ++i)
                gl_lds16(wsrc[i] + k0, &Bs[cur ^ 1][wldo[i]]);
        }
        // compute on buffer cur
        V16 af[4];
#pragma unroll
        for (int ks = 0; ks < 4; ++ks)
            af[ks].u = *(const uint4*)(&As[cur][arow * 128 + (((ks * 4 + lg) ^ (arow & 15)) * 8)]);
#pragma unroll
        for (int nj = 0; nj < 2; ++nj) {
            const int brow = wn * 32 + nj * 16 + l15;
#pragma unroll
            for (int ks = 0; ks < 4; ++ks) {
                V16 bf;
                bf.u = *(const uint4*)(&Bs[cur][brow * 128 + (((ks * 4 + lg) ^ (brow & 15)) * 8)]);
                acc[nj] = __builtin_amdgcn_mfma_f32_16x16x32_bf16(af[ks].b, bf.b, acc[nj], 0, 0, 0);
            }
        }
        if (t < 7) {  // convert + write next x tile
            uint4 xc;
            xc.x = f2b(xa.x) | ((unsigned)f2b(xa.y) << 16);
            xc.y = f2b(xa.z) | ((unsigned)f2b(xa.w) << 16);
            xc.z = f2b(xb.x) | ((unsigned)f2b(xb.y) << 16);
            xc.w = f2b(xb.z) | ((unsigned)f2b(xb.w) << 16);
            *(uint4*)(&As[cur ^ 1][axoff]) = xc;
        }
        __syncthreads();
    }

    // epilogue: row = r0 + wr*16 + lg*4 + r ; col = wn*32 + nj*16 + l15
    const int trow0 = r0 + wr * 16 + lg * 4;
    if (wn < 2) {
#pragma unroll
        for (int nj = 0; nj < 2; ++nj) {
            const int col = wn * 32 + nj * 16 + l15;
#pragma unroll
            for (int r = 0; r < 4; ++r)
                qb[(size_t)(trow0 + r) * 64 + col] = f2b(acc[nj][r]);
        }
    } else {
        const int b = r0 >> 11;
        const int tloc = (r0 & 2047) + wr * 16 + lg * 4;
#pragma unroll
        for (int nj = 0; nj < 2; ++nj) {
            const int d = (wn - 2) * 32 + nj * 16 + l15;
            uint2 p;
            p.x = f2b(acc[nj][0]) | ((unsigned)f2b(acc[nj][1]) << 16);
            p.y = f2b(acc[nj][2]) | ((unsigned)f2b(acc[nj][3]) << 16);
            *(uint2*)(vbT + (size_t)(b * 64 + d) * 2048 + tloc) = p;
        }
    }
}

// ---------------- kernel 2: causal flash attention (K == Q), bf16 MFMA ----------------
// 512 blocks, globally heavy-first: idx>>2 = heaviness rank, idx&3 = batch.
// Per block: 16 q-rows, 4 waves split 64-key tiles round-robin, merge at end.
// K-fragments prefetched one tile ahead; defer-max (THR=8) skips o-rescale.
__global__ __launch_bounds__(256) void attn_kernel(
    const unsigned short* __restrict__ qb, const unsigned short* __restrict__ vbT,
    float* __restrict__ out)
{
    __shared__ __align__(16) unsigned short Ps[4][16 * 64];
    __shared__ __align__(16) float Om[4][16][64];
    __shared__ float Mm[4][16];
    __shared__ float Lm[4][16];

    const int tid = threadIdx.x;
    const int w = tid >> 6, lane = tid & 63;
    const int l15 = lane & 15, lg = lane >> 4;
    const int chunk = 127 - (blockIdx.x >> 2);
    const int b = blockIdx.x & 3;
    const int qrow0 = chunk * 16;
    const unsigned short* qbb = qb + (size_t)b * T_SEQ * 64;
    const unsigned short* vbb = vbT + (size_t)b * 64 * T_SEQ;

    V16 qf[2];
#pragma unroll
    for (int ks = 0; ks < 2; ++ks)
        qf[ks].u = *(const uint4*)(qbb + (size_t)(qrow0 + l15) * 64 + ks * 32 + lg * 8);

    f32x4 o[4];
    float m[4], lv[4];
#pragma unroll
    for (int p = 0; p < 4; ++p)
#pragma unroll
        for (int j = 0; j < 4; ++j) o[p][j] = 0.f;
#pragma unroll
    for (int r = 0; r < 4; ++r) { m[r] = -1e30f; lv[r] = 0.f; }

    unsigned short* ps = Ps[w];
    const int ntiles = (qrow0 + 79) >> 6;

    V16 kf[4][2];
    if (w < ntiles) {
        const int s0 = w * 64;
#pragma unroll
        for (int nj = 0; nj < 4; ++nj)
#pragma unroll
            for (int ks = 0; ks < 2; ++ks)
                kf[nj][ks].u = *(const uint4*)(qbb + (size_t)(s0 + nj * 16 + l15) * 64 + ks * 32 + lg * 8);
    }

    for (int t = w; t < ntiles; t += 4) {
        const int s0 = t * 64;
        // QK^T with current K fragments
        f32x4 s[4];
#pragma unroll
        for (int nj = 0; nj < 4; ++nj) {
#pragma unroll
            for (int j = 0; j < 4; ++j) s[nj][j] = 0.f;
#pragma unroll
            for (int ks = 0; ks < 2; ++ks)
                s[nj] = __builtin_amdgcn_mfma_f32_16x16x32_bf16(qf[ks].b, kf[nj][ks].b, s[nj], 0, 0, 0);
        }
        // V fragments (latency hidden under softmax)
        V16 vf[4][2];
#pragma unroll
        for (int p = 0; p < 4; ++p)
#pragma unroll
            for (int ks = 0; ks < 2; ++ks)
                vf[p][ks].u = *(const uint4*)(vbb + (size_t)(p * 16 + l15) * 2048 + s0 + ks * 32 + lg * 8);
        // prefetch next K tile (hidden under softmax+PV)
        const int tn = t + 4;
        V16 kn[4][2];
        if (tn < ntiles) {
            const int sn = tn * 64;
#pragma unroll
            for (int nj = 0; nj < 4; ++nj)
#pragma unroll
                for (int ks = 0; ks < 2; ++ks)
                    kn[nj][ks].u = *(const uint4*)(qbb + (size_t)(sn + nj * 16 + l15) * 64 + ks * 32 + lg * 8);
        }

        // scale + causal mask (D: row = lg*4 + r, col = l15)
        if (s0 + 63 > qrow0) {
#pragma unroll
            for (int nj = 0; nj < 4; ++nj) {
                const int key = s0 + nj * 16 + l15;
#pragma unroll
                for (int r = 0; r < 4; ++r) {
                    float sv = s[nj][r] * 0.125f;
                    if (key > qrow0 + lg * 4 + r) sv = -1e30f;
                    s[nj][r] = sv;
                }
            }
        } else {
#pragma unroll
            for (int nj = 0; nj < 4; ++nj)
#pragma unroll
                for (int r = 0; r < 4; ++r) s[nj][r] *= 0.125f;
        }

        // online softmax with defer-max (rows live in 16-lane groups)
#pragma unroll
        for (int r = 0; r < 4; ++r) {
            float mc = fmaxf(fmaxf(s[0][r], s[1][r]), fmaxf(s[2][r], s[3][r]));
            mc = fmaxf(mc, __shfl_xor(mc, 1));
            mc = fmaxf(mc, __shfl_xor(mc, 2));
            mc = fmaxf(mc, __shfl_xor(mc, 4));
            mc = fmaxf(mc, __shfl_xor(mc, 8));
            if (mc > m[r] + 8.f) {           // rescale only on real max growth
                const float fr = __expf(m[r] - mc);
                m[r] = mc;
                lv[r] *= fr;
                o[0][r] *= fr; o[1][r] *= fr; o[2][r] *= fr; o[3][r] *= fr;
            }
        }
#pragma unroll
        for (int nj = 0; nj < 4; ++nj)
#pragma unroll
            for (int r = 0; r < 4; ++r) s[nj][r] = __expf(s[nj][r] - m[r]);
#pragma unroll
        for (int r = 0; r < 4; ++r) {
            float ls = s[0][r] + s[1][r] + s[2][r] + s[3][r];
            ls += __shfl_xor(ls, 1);
            ls += __shfl_xor(ls, 2);
            ls += __shfl_xor(ls, 4);
            ls += __shfl_xor(ls, 8);
            lv[r] += ls;
        }

        // P -> per-wave LDS [16][64] bf16, 16B-slot XOR swizzle
#pragma unroll
        for (int nj = 0; nj < 4; ++nj) {
            const int col = nj * 16 + l15;
            const int sl = col >> 3, cr = col & 7;
#pragma unroll
            for (int r = 0; r < 4; ++r) {
                const int row = lg * 4 + r;
                ps[row * 64 + ((sl ^ (row & 7)) << 3) + cr] = f2b(s[nj][r]);
            }
        }
        // PV
#pragma unroll
        for (int ks = 0; ks < 2; ++ks) {
            V16 pa;
            pa.u = *(const uint4*)((const unsigned char*)ps + l15 * 128 +
                                   (((((unsigned)ks << 2) | lg) ^ (unsigned)(l15 & 7)) << 4));
#pragma unroll
            for (int p = 0; p < 4; ++p)
                o[p] = __builtin_amdgcn_mfma_f32_16x16x32_bf16(pa.b, vf[p][ks].b, o[p], 0, 0, 0);
        }
        // rotate prefetched K
        if (tn < ntiles) {
#pragma unroll
            for (int nj = 0; nj < 4; ++nj)
#pragma unroll
                for (int ks = 0; ks < 2; ++ks) kf[nj][ks] = kn[nj][ks];
        }
    }

    // merge the 4 per-wave softmax states
#pragma unroll
    for (int p = 0; p < 4; ++p)
#pragma unroll
        for (int r = 0; r < 4; ++r)
            Om[w][lg * 4 + r][p * 16 + l15] = o[p][r];
    if (l15 == 0) {
#pragma unroll
        for (int r = 0; r < 4; ++r) { Mm[w][lg * 4 + r] = m[r]; Lm[w][lg * 4 + r] = lv[r]; }
    }
    __syncthreads();

    const int row = tid >> 4, d0 = (tid & 15) * 4;
    const float M = fmaxf(fmaxf(Mm[0][row], Mm[1][row]), fmaxf(Mm[2][row], Mm[3][row]));
    float L = 0.f;
    float ax = 0.f, ay = 0.f, az = 0.f, aw = 0.f;
#pragma unroll
    for (int ww = 0; ww < 4; ++ww) {
        const float e = __expf(Mm[ww][row] - M);
        L += e * Lm[ww][row];
        const float4 ov = *(const float4*)&Om[ww][row][d0];
        ax += e * ov.x; ay += e * ov.y; az += e * ov.z; aw += e * ov.w;
    }
    const float inv = 1.f / L;
    *(float4*)(out + ((size_t)b * T_SEQ + qrow0 + row) * 64 + d0) =
        make_float4(ax * inv, ay * inv, az * inv, aw * inv);
}

extern "C" void kernel_launch(void* const* d_in, const int* in_sizes, int n_in,
                              void* d_out, int out_size, void* d_ws, size_t ws_size,
                              hipStream_t stream) {
    const float* x  = (const float*)d_in[0];
    const float* Wq = (const float*)d_in[1];
    // d_in[2] = Wk: unused (reference bug: key = query projection)
    const float* Wv = (const float*)d_in[3];
    float* outp = (float*)d_out;

    unsigned short* qbw = (unsigned short*)d_ws;          // 1 MB
    unsigned short* vbw = qbw + 8192 * 64;                // 1 MB (v transposed)
    unsigned short* wbw = vbw + 8192 * 64;                // 256 KB ([Wq;Wv] bf16)

    wconv<<<64, 256, 0, stream>>>(Wq, Wv, wbw);
    proj_kernel<<<256, 512, 0, stream>>>(x, wbw, qbw, vbw);
    attn_kernel<<<512, 256, 0, stream>>>(qbw, vbw, outp);
}